// Round 7
// baseline (190.370 us; speedup 1.0000x reference)
//
#include <hip/hip_runtime.h>
#include <stdint.h>

#define BB 16
#define HH 512
#define WW 512
#define HWsz (HH*WW)

// exact left-to-right f32, no fma contraction: matches np's 0.299*r + 0.587*g + 0.114*b
__device__ __forceinline__ float grayf(float r,float g,float b){
  return __fadd_rn(__fadd_rn(__fmul_rn(0.299f,r),__fmul_rn(0.587f,g)),__fmul_rn(0.114f,b));
}
__device__ __forceinline__ float sigmoidf_(float x){ return 1.0f/(1.0f+expf(-x)); }

// offs order: (-1,0),(-1,1),(0,1),(1,1),(1,0),(1,-1),(0,-1),(-1,-1)
__device__ __forceinline__ int lbp_code(float tl,float tc,float tr,
                                        float ml,float c ,float mr,
                                        float bl,float bc,float br){
  int b0 = tc>=c, b1 = tr>=c, b2 = mr>=c, b3 = br>=c;
  int b4 = bc>=c, b5 = bl>=c, b6 = ml>=c, b7 = tl>=c;
  int s = (b0+b1)+(b2+b3)+(b4+b5)+(b6+b7);
  int tr_ = (b0!=b7)+(b1!=b0)+(b2!=b1)+(b3!=b2)+(b4!=b3)+(b5!=b4)+(b6!=b5)+(b7!=b6);
  return (tr_<=2)? s : 9;
}

// ---------------- K0: zero the tiny ws region ----------------
__global__ void k_init(float* sums, int* maxc){
  int t = threadIdx.x;
  if(t < BB*3) sums[t] = 0.0f;
  if(t < BB) maxc[t] = 0;
}

// ---------------- K1: per-image reductions (yuv sums + max LBP code) ----
// (unchanged — validated)
#define RSTRIDE 520
__global__ __launch_bounds__(256,4) void k_reduce(const float* __restrict__ frame,
     float* __restrict__ sums, int* __restrict__ maxc){
  const int blk = blockIdx.x;
  const int b = blk >> 6;
  const int s = blk & 63;
  const int r0 = s*8;
  const float4* F = (const float4*)(frame + (size_t)b*3*HWsz);
  __shared__ float sg[10*RSTRIDE];
  const int tid = threadIdx.x;
  float sy=0.f, su=0.f, sv=0.f;
  #pragma unroll
  for(int k=0;k<5;k++){
    int j = tid + 256*k;
    int row = j >> 7;
    int c4  = j & 127;
    int gy  = min(max(r0-1+row,0),HH-1);
    int fi  = gy*128 + c4;
    float4 r4 = F[fi];
    float4 g4 = F[65536  + fi];
    float4 b4 = F[131072 + fi];
    float4 gr;
    gr.x = grayf(r4.x,g4.x,b4.x);
    gr.y = grayf(r4.y,g4.y,b4.y);
    gr.z = grayf(r4.z,g4.z,b4.z);
    gr.w = grayf(r4.w,g4.w,b4.w);
    *(float4*)&sg[row*RSTRIDE + 4 + 4*c4] = gr;
    if(c4==0)   sg[row*RSTRIDE + 3]   = gr.x;
    if(c4==127) sg[row*RSTRIDE + 516] = gr.w;
    if(row>=1 && row<=8){
      sy += (gr.x+gr.y)+(gr.z+gr.w);
      float rs_=(r4.x+r4.y)+(r4.z+r4.w), gs_=(g4.x+g4.y)+(g4.z+g4.w), bs_=(b4.x+b4.y)+(b4.z+b4.w);
      su += -0.147f*rs_ - 0.289f*gs_ + 0.436f*bs_;
      sv +=  0.615f*rs_ - 0.515f*gs_ - 0.1f*bs_;
    }
  }
  __syncthreads();
  int cm = 0;
  {
    const float* base = sg + (2*tid + 3);
    float t0=base[0], t1=base[1], t2=base[2], t3=base[3];
    float m0=base[RSTRIDE], m1=base[RSTRIDE+1], m2=base[RSTRIDE+2], m3=base[RSTRIDE+3];
    #pragma unroll
    for(int R=1;R<=8;R++){
      const float* brow = base + (R+1)*RSTRIDE;
      float b0=brow[0], b1=brow[1], b2=brow[2], b3=brow[3];
      cm = max(cm, lbp_code(t0,t1,t2, m0,m1,m2, b0,b1,b2));
      cm = max(cm, lbp_code(t1,t2,t3, m1,m2,m3, b1,b2,b3));
      t0=m0;t1=m1;t2=m2;t3=m3; m0=b0;m1=b1;m2=b2;m3=b3;
    }
  }
  #pragma unroll
  for(int off=32;off>=1;off>>=1){
    sy += __shfl_down(sy,off,64);
    su += __shfl_down(su,off,64);
    sv += __shfl_down(sv,off,64);
    cm = max(cm,__shfl_down(cm,off,64));
  }
  __shared__ float rs[3][4]; __shared__ int rm[4];
  int wave=tid>>6, lane=tid&63;
  if(lane==0){ rs[0][wave]=sy; rs[1][wave]=su; rs[2][wave]=sv; rm[wave]=cm; }
  __syncthreads();
  if(tid==0){
    atomicAdd(&sums[b*3+0], (rs[0][0]+rs[0][1])+(rs[0][2]+rs[0][3]));
    atomicAdd(&sums[b*3+1], (rs[1][0]+rs[1][1])+(rs[1][2]+rs[1][3]));
    atomicAdd(&sums[b*3+2], (rs[2][0]+rs[2][1])+(rs[2][2]+rs[2][3]));
    atomicMax(&maxc[b], max(max(rm[0],rm[1]),max(rm[2],rm[3])));
  }
}

// ---------------- K2: channel-attention MLP (tiny) ----------------
__global__ void k_scale(const float* __restrict__ sums, const int* __restrict__ maxc,
    const float* __restrict__ w1, const float* __restrict__ w2,
    float* __restrict__ scale, float* __restrict__ mxf){
  int b = threadIdx.x;
  if(b >= BB) return;
  float p[3], h[3];
  for(int j=0;j<3;j++) p[j] = sums[b*3+j] * (1.0f/(float)HWsz);
  for(int i=0;i<3;i++){
    float a = p[0]*w1[i*3+0] + p[1]*w1[i*3+1] + p[2]*w1[i*3+2];
    h[i] = fmaxf(a, 0.0f);
  }
  for(int i=0;i<3;i++){
    float a = h[0]*w2[i*3+0] + h[1]*w2[i*3+1] + h[2]*w2[i*3+2];
    scale[b*3+i] = sigmoidf_(a);
  }
  mxf[b] = fmaxf((float)maxc[b], 1.0f);
}

// ---------------- K3: fused conv + mask + strength + watermark + RGB ----
// Round-7: staging + LBP verbatim from round 6 (ran & passed on HW).
// Conv restructured to COLUMN-SLIDING with lane-stride-1 scalar LDS reads —
// the only access shape measured conflict-free on this HW (m136 pattern).
// Thread = (col x = tid&63, band = tid>>6); band == one wave; 8 out rows per
// thread. Per (ci, input row i of 14): tap[7] at staged cols x+1..x+7
// (stride-1 across the wave); row i contributes to out rows r=i-6..i via
// ky=i-r. conv reads 49/px, FMA structural 196/px. ci is a RUNTIME loop
// (code fits I-cache); i,r fully unrolled -> acc[8] statically indexed.
// Strength: thread owns 8 rows of one col of its 8x8 block -> shfl_xor 1,2,4.
// Final pass + stores also lane-stride-1 / coalesced.
#define SAS 73   // 72 staged cols (64 + 2*4 halo) + 1 pad
__global__ __launch_bounds__(256,3) void k_main(const float* __restrict__ frame,
    const int* __restrict__ wm, const float* __restrict__ sa_w, const float* __restrict__ sa_b,
    const float* __restrict__ scalev, const float* __restrict__ mxf,
    float* __restrict__ out)
{
  const int b = blockIdx.z;
  const int tx0 = blockIdx.x*64, ty0 = blockIdx.y*32;
  const float* fr = frame + (size_t)b*3*HWsz;
  const float4* F4 = (const float4*)fr;

  __shared__ float sA[4][38][SAS];  // ch 0..2: zero-padded rgb; ch 3: gray(clamped) then lbp
  __shared__ float sgt[76];         // clamped gray row gy = ty0-4
  __shared__ float sgb[76];         // clamped gray row gy = ty0+35
  __shared__ float ssc[4];          // 0..2 scale, 3 bias
  __shared__ float scodetab[12];    // code/mx lookup

  const int tid = threadIdx.x;
  if(tid < 3)  ssc[tid] = scalev[b*3 + tid];
  if(tid == 3) ssc[3] = sa_b[0];
  if(tid < 10) scodetab[tid] = (float)tid / mxf[b];

  // ---- staging: 40 rows (gy=ty0-4+ly) x 18 f4-cols (gx0=tx0-4+4k) ----
  for(int s = tid; s < 720; s += 256){
    int ly = s / 18;            // 0..39
    int k  = s - ly*18;         // 0..17
    int gy = ty0 + ly - 4;
    int ry = min(max(gy,0),HH-1);
    int gx0 = tx0 + 4*k - 4;
    bool xin = (gx0 >= 0) && (gx0 <= WW-4);
    float4 r4, g4, b4;
    if(xin){
      int fi = ry*(WW/4) + (gx0>>2);
      r4 = F4[fi]; g4 = F4[65536 + fi]; b4 = F4[131072 + fi];
    } else {
      // fully-outside slot: all 4 columns clamp to the same edge column
      int cc = (gx0 < 0) ? 0 : (WW-1);
      float r = fr[ry*WW+cc], g = fr[HWsz+ry*WW+cc], bl = fr[2*HWsz+ry*WW+cc];
      r4 = make_float4(r,r,r,r); g4 = make_float4(g,g,g,g); b4 = make_float4(bl,bl,bl,bl);
    }
    float gr0 = grayf(r4.x,g4.x,b4.x), gr1 = grayf(r4.y,g4.y,b4.y),
          gr2 = grayf(r4.z,g4.z,b4.z), gr3 = grayf(r4.w,g4.w,b4.w);
    int cbase = 4*k;
    float* gp = (ly==0) ? &sgt[cbase] : ((ly==39) ? &sgb[cbase] : &sA[3][ly-1][cbase]);
    gp[0]=gr0; gp[1]=gr1; gp[2]=gr2; gp[3]=gr3;
    if(ly >= 1 && ly <= 38){
      float z = ((gy >= 0) && (gy < HH) && xin) ? 1.0f : 0.0f;  // conv zero-pad
      float* rp = &sA[0][ly-1][cbase];
      rp[0]          =r4.x*z; rp[1]          =r4.y*z; rp[2]          =r4.z*z; rp[3]          =r4.w*z;
      rp[38*SAS+0]   =g4.x*z; rp[38*SAS+1]   =g4.y*z; rp[38*SAS+2]   =g4.z*z; rp[38*SAS+3]   =g4.w*z;
      rp[2*38*SAS+0] =b4.x*z; rp[2*38*SAS+1] =b4.y*z; rp[2*38*SAS+2] =b4.z*z; rp[2*38*SAS+3] =b4.w*z;
    }
  }
  __syncthreads();

  // ---- LBP: compute from gray (sA[3] + side rows) into registers ----
  // 684 slots = 38 rows x 18 groups of 4 px. Reads at col 4q-1..4q+4; the
  // out-of-range reads (col -1 / 72) feed only masked-out pixels.
  float lv[3][4];
  #pragma unroll
  for(int it=0; it<3; ++it){
    int s2 = tid + 256*it;
    if(s2 < 684){
      int lr = s2 / 18;
      int q  = s2 - lr*18;
      int lx0 = 4*q;
      const float* rowM = &sA[3][lr][0];
      const float* rowT = (lr==0)  ? sgt : &sA[3][lr-1][0];
      const float* rowB = (lr==37) ? sgb : &sA[3][lr+1][0];
      float t_[6], m_[6], b_[6];
      #pragma unroll
      for(int j=0;j<6;j++){
        int c = lx0 - 1 + j;
        t_[j]=rowT[c]; m_[j]=rowM[c]; b_[j]=rowB[c];
      }
      int gy = ty0 + lr - 3;
      bool rowin = (gy >= 0) && (gy < HH);
      #pragma unroll
      for(int j=0;j<4;j++){
        int lx = lx0 + j;
        int gx = tx0 + lx - 4;
        float v = 0.0f;
        if(rowin && lx >= 1 && lx <= 70 && gx >= 0 && gx < WW){
          float c = m_[j+1];
          // bit order: tc,tr,mr,br,bc,bl,ml,tl (matches offs order)
          int msk = ((t_[j+1]>=c)?1:0)   | ((t_[j+2]>=c)?2:0)  | ((m_[j+2]>=c)?4:0) |
                    ((b_[j+2]>=c)?8:0)   | ((b_[j+1]>=c)?16:0) | ((b_[j]>=c)?32:0)  |
                    ((m_[j]>=c)?64:0)    | ((t_[j]>=c)?128:0);
          int s8  = __popc(msk);
          int rot = ((msk<<1) | (msk>>7)) & 255;
          int tr_ = __popc(msk ^ rot);
          int code = (tr_ <= 2) ? s8 : 9;
          v = scodetab[code];
        }
        lv[it][j] = v;
      }
    }
  }
  __syncthreads();
  #pragma unroll
  for(int it=0; it<3; ++it){
    int s2 = tid + 256*it;
    if(s2 < 684){
      int lr = s2 / 18;
      int q  = s2 - lr*18;
      float* wp2 = &sA[3][lr][4*q];
      wp2[0]=lv[it][0]; wp2[1]=lv[it][1]; wp2[2]=lv[it][2]; wp2[3]=lv[it][3];
    }
  }
  __syncthreads();

  // ---- column-sliding 7x7x4 conv; lane-stride-1 scalar LDS taps ----
  const int x    = tid & 63;       // column 0..63 (lane)
  const int band = tid >> 6;       // 0..3, == wave id
  const int r0s  = band*8;         // staged-row base of this band's window
  float acc[8];
  {
    const float bias = ssc[3];
    #pragma unroll
    for(int r=0;r<8;r++) acc[r]=bias;
  }
  for(int ci=0;ci<4;ci++){
    const float* chan = &sA[ci][0][0] + (r0s)*SAS + (x+1);
    const float* wci  = &sa_w[ci*49];
    #pragma unroll
    for(int i=0;i<14;i++){
      const float* rowp = chan + i*SAS;
      float tap[7];
      #pragma unroll
      for(int k=0;k<7;k++) tap[k]=rowp[k];
      #pragma unroll
      for(int r=0;r<8;r++){
        const int ky = i - r;
        if(ky >= 0 && ky <= 6){
          const float* wr = wci + ky*7;
          acc[r] += tap[0]*wr[0]+tap[1]*wr[1]+tap[2]*wr[2]+tap[3]*wr[3]
                  + tap[4]*wr[4]+tap[5]*wr[5]+tap[6]*wr[6];
        }
      }
    }
  }
  float m[8];
  float msum = 0.f;
  #pragma unroll
  for(int r=0;r<8;r++){ m[r]=sigmoidf_(acc[r]); msum += m[r]; }
  {
    size_t mbase = (size_t)(3*BB)*HWsz + (size_t)b*HWsz + (size_t)(ty0+r0s)*WW + (size_t)(tx0+x);
    #pragma unroll
    for(int r=0;r<8;r++) out[mbase + (size_t)r*WW] = m[r];
  }

  // strength: 8x8 block mean. Thread holds its column's 8 rows (all in block
  // row = band); sum over the 8 columns of the x-oct -> shfl_xor 1,2,4.
  msum += __shfl_xor(msum, 1, 64);
  msum += __shfl_xor(msum, 2, 64);
  msum += __shfl_xor(msum, 4, 64);
  const float strength = msum * (1.0f/64.0f);

  // final: weighted yuv + rank-1 DCT delta -> rgb (lane-stride-1 LDS reads)
  {
    const float sc0=ssc[0], sc1=ssc[1], sc2=ssc[2];
    const float sgn = (float)(2*wm[(tx0+x)>>3]-1);
    const float D3tab[8] = { 0.4157348061512726f,-0.0975451610080641f,-0.4903926402016152f,-0.2777851165098011f,
                             0.2777851165098011f, 0.4903926402016152f, 0.0975451610080641f,-0.4157348061512726f };
    const float dcol = D3tab[x & 7];
    #pragma unroll
    for(int r=0;r<8;r++){
      const int rl = r0s + r;          // local out row 0..31
      float rr = sA[0][rl+3][x+4];
      float gg = sA[1][rl+3][x+4];
      float bb = sA[2][rl+3][x+4];
      float yv = (0.299f*rr + 0.587f*gg + 0.114f*bb) * sc0;
      float uv = (-0.147f*rr - 0.289f*gg + 0.436f*bb) * sc1;
      float vv = ( 0.615f*rr - 0.515f*gg - 0.1f*bb) * sc2;
      float d4 = (((rl+1)&2) ? -0.35355339059327373f : 0.35355339059327373f);
      float delta = 0.05f * strength * sgn * d4;
      float ym = yv + delta * dcol;
      float vr = ym + 1.14f*vv;
      float vg = ym - 0.395f*uv - 0.581f*vv;
      float vb = ym + 2.032f*uv;
      size_t base = (size_t)(ty0+rl)*WW + (size_t)(tx0+x);
      out[(size_t)(b*3+0)*HWsz + base] = vr;
      out[(size_t)(b*3+1)*HWsz + base] = vg;
      out[(size_t)(b*3+2)*HWsz + base] = vb;
    }
  }
}

extern "C" void kernel_launch(void* const* d_in, const int* in_sizes, int n_in,
                              void* d_out, int out_size, void* d_ws, size_t ws_size,
                              hipStream_t stream) {
  const float* frame = (const float*)d_in[0];
  const int*   wmark = (const int*)d_in[1];
  const float* sa_w  = (const float*)d_in[2];
  const float* sa_b  = (const float*)d_in[3];
  const float* ca_w1 = (const float*)d_in[4];
  const float* ca_w2 = (const float*)d_in[5];
  float* out = (float*)d_out;
  char* ws = (char*)d_ws;
  float* sums  = (float*)(ws);        // 48 f32
  int*   maxc  = (int*)(ws + 192);    // 16 int
  float* scalev= (float*)(ws + 256);  // 48 f32
  float* mxf   = (float*)(ws + 448);  // 16 f32

  hipLaunchKernelGGL(k_init,  dim3(1),        dim3(64),  0, stream, sums, maxc);
  hipLaunchKernelGGL(k_reduce,dim3(1024),     dim3(256), 0, stream, frame, sums, maxc);
  hipLaunchKernelGGL(k_scale, dim3(1),        dim3(64),  0, stream, sums, maxc, ca_w1, ca_w2, scalev, mxf);
  hipLaunchKernelGGL(k_main,  dim3(8,16,16),  dim3(256), 0, stream, frame, wmark, sa_w, sa_b, scalev, mxf, out);
}

// Round 8
// 152.319 us; speedup vs baseline: 1.2498x; 1.2498x over previous
//
#include <hip/hip_runtime.h>
#include <stdint.h>

#define BB 16
#define HH 512
#define WW 512
#define HWsz (HH*WW)

// exact left-to-right f32, no fma contraction: matches np's 0.299*r + 0.587*g + 0.114*b
__device__ __forceinline__ float grayf(float r,float g,float b){
  return __fadd_rn(__fadd_rn(__fmul_rn(0.299f,r),__fmul_rn(0.587f,g)),__fmul_rn(0.114f,b));
}
__device__ __forceinline__ float sigmoidf_(float x){ return 1.0f/(1.0f+expf(-x)); }

// offs order: (-1,0),(-1,1),(0,1),(1,1),(1,0),(1,-1),(0,-1),(-1,-1)
__device__ __forceinline__ int lbp_code(float tl,float tc,float tr,
                                        float ml,float c ,float mr,
                                        float bl,float bc,float br){
  int b0 = tc>=c, b1 = tr>=c, b2 = mr>=c, b3 = br>=c;
  int b4 = bc>=c, b5 = bl>=c, b6 = ml>=c, b7 = tl>=c;
  int s = (b0+b1)+(b2+b3)+(b4+b5)+(b6+b7);
  int tr_ = (b0!=b7)+(b1!=b0)+(b2!=b1)+(b3!=b2)+(b4!=b3)+(b5!=b4)+(b6!=b5)+(b7!=b6);
  return (tr_<=2)? s : 9;
}

// ---------------- K1: per-image partial reductions (yuv sums + max LBP code) ----
// Body identical to the validated k_reduce; tail writes a per-block float4
// partial instead of atomics -> no zero-init kernel needed, no k_scale.
#define RSTRIDE 520
__global__ __launch_bounds__(256,4) void k_reduce(const float* __restrict__ frame,
     float4* __restrict__ part){
  const int blk = blockIdx.x;
  const int b = blk >> 6;
  const int s = blk & 63;
  const int r0 = s*8;
  const float4* F = (const float4*)(frame + (size_t)b*3*HWsz);
  __shared__ float sg[10*RSTRIDE];
  const int tid = threadIdx.x;
  float sy=0.f, su=0.f, sv=0.f;
  #pragma unroll
  for(int k=0;k<5;k++){
    int j = tid + 256*k;
    int row = j >> 7;
    int c4  = j & 127;
    int gy  = min(max(r0-1+row,0),HH-1);
    int fi  = gy*128 + c4;
    float4 r4 = F[fi];
    float4 g4 = F[65536  + fi];
    float4 b4 = F[131072 + fi];
    float4 gr;
    gr.x = grayf(r4.x,g4.x,b4.x);
    gr.y = grayf(r4.y,g4.y,b4.y);
    gr.z = grayf(r4.z,g4.z,b4.z);
    gr.w = grayf(r4.w,g4.w,b4.w);
    *(float4*)&sg[row*RSTRIDE + 4 + 4*c4] = gr;
    if(c4==0)   sg[row*RSTRIDE + 3]   = gr.x;
    if(c4==127) sg[row*RSTRIDE + 516] = gr.w;
    if(row>=1 && row<=8){
      sy += (gr.x+gr.y)+(gr.z+gr.w);
      float rs_=(r4.x+r4.y)+(r4.z+r4.w), gs_=(g4.x+g4.y)+(g4.z+g4.w), bs_=(b4.x+b4.y)+(b4.z+b4.w);
      su += -0.147f*rs_ - 0.289f*gs_ + 0.436f*bs_;
      sv +=  0.615f*rs_ - 0.515f*gs_ - 0.1f*bs_;
    }
  }
  __syncthreads();
  int cm = 0;
  {
    const float* base = sg + (2*tid + 3);
    float t0=base[0], t1=base[1], t2=base[2], t3=base[3];
    float m0=base[RSTRIDE], m1=base[RSTRIDE+1], m2=base[RSTRIDE+2], m3=base[RSTRIDE+3];
    #pragma unroll
    for(int R=1;R<=8;R++){
      const float* brow = base + (R+1)*RSTRIDE;
      float b0=brow[0], b1=brow[1], b2=brow[2], b3=brow[3];
      cm = max(cm, lbp_code(t0,t1,t2, m0,m1,m2, b0,b1,b2));
      cm = max(cm, lbp_code(t1,t2,t3, m1,m2,m3, b1,b2,b3));
      t0=m0;t1=m1;t2=m2;t3=m3; m0=b0;m1=b1;m2=b2;m3=b3;
    }
  }
  #pragma unroll
  for(int off=32;off>=1;off>>=1){
    sy += __shfl_down(sy,off,64);
    su += __shfl_down(su,off,64);
    sv += __shfl_down(sv,off,64);
    cm = max(cm,__shfl_down(cm,off,64));
  }
  __shared__ float rs[3][4]; __shared__ int rm[4];
  int wave=tid>>6, lane=tid&63;
  if(lane==0){ rs[0][wave]=sy; rs[1][wave]=su; rs[2][wave]=sv; rm[wave]=cm; }
  __syncthreads();
  if(tid==0){
    part[blk] = make_float4((rs[0][0]+rs[0][1])+(rs[0][2]+rs[0][3]),
                            (rs[1][0]+rs[1][1])+(rs[1][2]+rs[1][3]),
                            (rs[2][0]+rs[2][1])+(rs[2][2]+rs[2][3]),
                            (float)max(max(rm[0],rm[1]),max(rm[2],rm[3])));
  }
}

// ---------------- K2: fused head-reduce + conv + mask + strength + watermark + RGB ----
// k_main body = round-1 validated kernel (55.3us) VERBATIM, except the
// ssc/scodetab fill is replaced by an inline wave0 head: 64 lanes load this
// image's 64 partials, 6-step shfl_xor butterfly (sum x3 / fmax), every lane
// computes the 3x3 MLP (uniform scalar loads), lanes 0..3 fill ssc, lanes
// 0..9 fill scodetab from in-register mx. Staging barrier covers visibility.
#define SAS 41
__global__ __launch_bounds__(256,6) void k_main(const float* __restrict__ frame,
    const int* __restrict__ wm, const float* __restrict__ sa_w, const float* __restrict__ sa_b,
    const float* __restrict__ ca_w1, const float* __restrict__ ca_w2,
    const float4* __restrict__ part, float* __restrict__ out)
{
  const int b = blockIdx.z;
  const int tx0 = blockIdx.x*32, ty0 = blockIdx.y*32;
  const float* fr = frame + (size_t)b*3*HWsz;
  const float4* F4 = (const float4*)fr;

  __shared__ float sA[4][38][SAS];  // ch 0..2: zero-padded rgb; ch 3: gray(clamped) then lbp
  __shared__ float sgt[44];         // clamped gray row gy = ty0-4
  __shared__ float sgb[44];         // clamped gray row gy = ty0+35
  __shared__ float ssc[4];          // 0..2 scale, 3 bias
  __shared__ float scodetab[12];    // code/mx lookup

  const int tid = threadIdx.x;

  // ---- head: reduce 64 partials -> pooled yuv + mx; MLP -> scale ----
  if(tid < 64){
    float4 p4 = part[b*64 + tid];
    float sy=p4.x, su=p4.y, sv=p4.z, cmf=p4.w;
    #pragma unroll
    for(int off=1; off<64; off<<=1){
      sy  += __shfl_xor(sy,  off, 64);
      su  += __shfl_xor(su,  off, 64);
      sv  += __shfl_xor(sv,  off, 64);
      cmf  = fmaxf(cmf, __shfl_xor(cmf, off, 64));
    }
    float mx = fmaxf(cmf, 1.0f);
    float p0 = sy * (1.0f/(float)HWsz);
    float p1 = su * (1.0f/(float)HWsz);
    float p2 = sv * (1.0f/(float)HWsz);
    float h0 = fmaxf(p0*ca_w1[0] + p1*ca_w1[1] + p2*ca_w1[2], 0.0f);
    float h1 = fmaxf(p0*ca_w1[3] + p1*ca_w1[4] + p2*ca_w1[5], 0.0f);
    float h2 = fmaxf(p0*ca_w1[6] + p1*ca_w1[7] + p2*ca_w1[8], 0.0f);
    if(tid < 3){
      float a = h0*ca_w2[tid*3+0] + h1*ca_w2[tid*3+1] + h2*ca_w2[tid*3+2];
      ssc[tid] = sigmoidf_(a);
    }
    if(tid == 3) ssc[3] = sa_b[0];
    if(tid < 10) scodetab[tid] = (float)tid / mx;
  }

  // ---- staging: 40 rows (gy=ty0-4+ly) x 10 f4-cols (gx0=tx0-4+4k) ----
  for(int s = tid; s < 400; s += 256){
    int ly = s / 10;            // 0..39
    int k  = s - ly*10;         // 0..9
    int gy = ty0 + ly - 4;
    int ry = min(max(gy,0),HH-1);
    int gx0 = tx0 + 4*k - 4;
    bool xin = (gx0 >= 0) && (gx0 <= WW-4);
    float4 r4, g4, b4;
    if(xin){
      int fi = ry*(WW/4) + (gx0>>2);
      r4 = F4[fi]; g4 = F4[65536 + fi]; b4 = F4[131072 + fi];
    } else {
      // fully-outside slot: all 4 columns clamp to the same edge column
      int cc = (gx0 < 0) ? 0 : (WW-1);
      float r = fr[ry*WW+cc], g = fr[HWsz+ry*WW+cc], bl = fr[2*HWsz+ry*WW+cc];
      r4 = make_float4(r,r,r,r); g4 = make_float4(g,g,g,g); b4 = make_float4(bl,bl,bl,bl);
    }
    float gr0 = grayf(r4.x,g4.x,b4.x), gr1 = grayf(r4.y,g4.y,b4.y),
          gr2 = grayf(r4.z,g4.z,b4.z), gr3 = grayf(r4.w,g4.w,b4.w);
    int cbase = 4*k;
    float* gp = (ly==0) ? &sgt[cbase] : ((ly==39) ? &sgb[cbase] : &sA[3][ly-1][cbase]);
    gp[0]=gr0; gp[1]=gr1; gp[2]=gr2; gp[3]=gr3;
    if(ly >= 1 && ly <= 38){
      float z = ((gy >= 0) && (gy < HH) && xin) ? 1.0f : 0.0f;  // conv zero-pad
      float* rp = &sA[0][ly-1][cbase];
      rp[0]          =r4.x*z; rp[1]          =r4.y*z; rp[2]          =r4.z*z; rp[3]          =r4.w*z;
      rp[38*SAS+0]   =g4.x*z; rp[38*SAS+1]   =g4.y*z; rp[38*SAS+2]   =g4.z*z; rp[38*SAS+3]   =g4.w*z;
      rp[2*38*SAS+0] =b4.x*z; rp[2*38*SAS+1] =b4.y*z; rp[2*38*SAS+2] =b4.z*z; rp[2*38*SAS+3] =b4.w*z;
    }
  }
  __syncthreads();

  // ---- LBP: compute from gray (sA[3] + side rows) into registers ----
  // 380 slots = 38 rows x 10 groups of 4 px. Reads at col 4q-1..4q+4; the
  // out-of-range reads (col -1 / 40,41) feed only masked-out pixels.
  float lv[2][4];
  #pragma unroll
  for(int it=0; it<2; ++it){
    int s2 = tid + 256*it;
    if(s2 < 380){
      int lr = s2 / 10;
      int q  = s2 - lr*10;
      int lx0 = 4*q;
      const float* rowM = &sA[3][lr][0];
      const float* rowT = (lr==0)  ? sgt : &sA[3][lr-1][0];
      const float* rowB = (lr==37) ? sgb : &sA[3][lr+1][0];
      float t_[6], m_[6], b_[6];
      #pragma unroll
      for(int j=0;j<6;j++){
        int c = lx0 - 1 + j;
        t_[j]=rowT[c]; m_[j]=rowM[c]; b_[j]=rowB[c];
      }
      int gy = ty0 + lr - 3;
      bool rowin = (gy >= 0) && (gy < HH);
      #pragma unroll
      for(int j=0;j<4;j++){
        int lx = lx0 + j;
        int gx = tx0 + lx - 4;
        float v = 0.0f;
        if(rowin && lx >= 1 && lx <= 38 && gx >= 0 && gx < WW){
          float c = m_[j+1];
          // bit order: tc,tr,mr,br,bc,bl,ml,tl (matches offs order)
          int msk = ((t_[j+1]>=c)?1:0)   | ((t_[j+2]>=c)?2:0)  | ((m_[j+2]>=c)?4:0) |
                    ((b_[j+2]>=c)?8:0)   | ((b_[j+1]>=c)?16:0) | ((b_[j]>=c)?32:0)  |
                    ((m_[j]>=c)?64:0)    | ((t_[j]>=c)?128:0);
          int s8  = __popc(msk);
          int rot = ((msk<<1) | (msk>>7)) & 255;
          int tr_ = __popc(msk ^ rot);
          int code = (tr_ <= 2) ? s8 : 9;
          v = scodetab[code];
        }
        lv[it][j] = v;
      }
    }
  }
  __syncthreads();
  #pragma unroll
  for(int it=0; it<2; ++it){
    int s2 = tid + 256*it;
    if(s2 < 380){
      int lr = s2 / 10;
      int q  = s2 - lr*10;
      float* wp2 = &sA[3][lr][4*q];
      wp2[0]=lv[it][0]; wp2[1]=lv[it][1]; wp2[2]=lv[it][2]; wp2[3]=lv[it][3];
    }
  }
  __syncthreads();

  // 7x7x4 conv; thread = (row ty, col-group t of 4 pixels). Scalar window loads.
  const int t  = tid & 7;
  const int ty = tid >> 3;
  float a0=ssc[3], a1=ssc[3], a2=ssc[3], a3=ssc[3];
  for(int ci=0;ci<4;ci++){
    #pragma unroll
    for(int ky=0;ky<7;ky++){
      const float* rowp = &sA[ci][ty+ky][4*t];
      float win[10];
      #pragma unroll
      for(int w=0;w<10;w++) win[w]=rowp[1+w];
      const float* wr = &sa_w[ci*49 + ky*7];
      #pragma unroll
      for(int kx=0;kx<7;kx++){
        float wt = wr[kx];
        a0 += win[kx+0]*wt;
        a1 += win[kx+1]*wt;
        a2 += win[kx+2]*wt;
        a3 += win[kx+3]*wt;
      }
    }
  }
  float m0=sigmoidf_(a0), m1=sigmoidf_(a1), m2=sigmoidf_(a2), m3=sigmoidf_(a3);
  {
    size_t midx = (size_t)(3*BB)*HWsz + (size_t)b*HWsz + (size_t)(ty0+ty)*WW + (size_t)(tx0+4*t);
    *reinterpret_cast<float4*>(out + midx) = make_float4(m0,m1,m2,m3);
  }

  // strength: mean of mask per 8x8 block via in-wave butterfly.
  // lane = ty_lo*8 + t (ty_lo = ty&7); 8x8 block (rb=wave, cb=t>>1) = all ty
  // in wave x t-pair -> xor masks 1 (t lsb), 8,16,32 (ty bits). No barrier.
  float partl = (m0+m1)+(m2+m3);
  partl += __shfl_xor(partl, 1, 64);
  partl += __shfl_xor(partl, 8, 64);
  partl += __shfl_xor(partl, 16, 64);
  partl += __shfl_xor(partl, 32, 64);
  const float strength = partl * (1.0f/64.0f);

  // final: weighted yuv + rank-1 DCT delta -> rgb (scalar LDS reads)
  {
    const float sc0=ssc[0], sc1=ssc[1], sc2=ssc[2];
    const int bw = (tx0 + 4*t) >> 3;
    const float sgn = (float)(2*wm[bw]-1);
    const float d4 = (((ty+1)&2) ? -0.35355339059327373f : 0.35355339059327373f);
    const float delta = 0.05f * strength * sgn * d4;
    const float D3tab[8] = { 0.4157348061512726f,-0.0975451610080641f,-0.4903926402016152f,-0.2777851165098011f,
                             0.2777851165098011f, 0.4903926402016152f, 0.0975451610080641f,-0.4157348061512726f };
    float vr[4], vg[4], vb[4];
    #pragma unroll
    for(int j=0;j<4;j++){
      float r  = sA[0][ty+3][4*t+j+4];
      float g  = sA[1][ty+3][4*t+j+4];
      float bl = sA[2][ty+3][4*t+j+4];
      float yv = (0.299f*r + 0.587f*g + 0.114f*bl) * sc0;
      float uv = (-0.147f*r - 0.289f*g + 0.436f*bl) * sc1;
      float vv = ( 0.615f*r - 0.515f*g - 0.1f*bl) * sc2;
      float ym = yv + delta * D3tab[(t&1)*4 + j];
      vr[j] = ym + 1.14f*vv;
      vg[j] = ym - 0.395f*uv - 0.581f*vv;
      vb[j] = ym + 2.032f*uv;
    }
    size_t base = (size_t)(ty0+ty)*WW + (size_t)(tx0+4*t);
    *reinterpret_cast<float4*>(out + (size_t)(b*3+0)*HWsz + base) = make_float4(vr[0],vr[1],vr[2],vr[3]);
    *reinterpret_cast<float4*>(out + (size_t)(b*3+1)*HWsz + base) = make_float4(vg[0],vg[1],vg[2],vg[3]);
    *reinterpret_cast<float4*>(out + (size_t)(b*3+2)*HWsz + base) = make_float4(vb[0],vb[1],vb[2],vb[3]);
  }
}

extern "C" void kernel_launch(void* const* d_in, const int* in_sizes, int n_in,
                              void* d_out, int out_size, void* d_ws, size_t ws_size,
                              hipStream_t stream) {
  const float* frame = (const float*)d_in[0];
  const int*   wmark = (const int*)d_in[1];
  const float* sa_w  = (const float*)d_in[2];
  const float* sa_b  = (const float*)d_in[3];
  const float* ca_w1 = (const float*)d_in[4];
  const float* ca_w2 = (const float*)d_in[5];
  float* out = (float*)d_out;
  float4* part = (float4*)d_ws;   // 1024 float4 partials = 16 KB

  hipLaunchKernelGGL(k_reduce, dim3(1024),      dim3(256), 0, stream, frame, part);
  hipLaunchKernelGGL(k_main,   dim3(16,16,16),  dim3(256), 0, stream, frame, wmark, sa_w, sa_b, ca_w1, ca_w2, part, out);
}

// Round 10
// 151.272 us; speedup vs baseline: 1.2585x; 1.0069x over previous
//
#include <hip/hip_runtime.h>
#include <stdint.h>

#define BB 16
#define HH 512
#define WW 512
#define HWsz (HH*WW)

// exact left-to-right f32, no fma contraction: matches np's 0.299*r + 0.587*g + 0.114*b
__device__ __forceinline__ float grayf(float r,float g,float b){
  return __fadd_rn(__fadd_rn(__fmul_rn(0.299f,r),__fmul_rn(0.587f,g)),__fmul_rn(0.114f,b));
}
__device__ __forceinline__ float sigmoidf_(float x){ return 1.0f/(1.0f+expf(-x)); }

// offs order: (-1,0),(-1,1),(0,1),(1,1),(1,0),(1,-1),(0,-1),(-1,-1)
__device__ __forceinline__ int lbp_code(float tl,float tc,float tr,
                                        float ml,float c ,float mr,
                                        float bl,float bc,float br){
  int b0 = tc>=c, b1 = tr>=c, b2 = mr>=c, b3 = br>=c;
  int b4 = bc>=c, b5 = bl>=c, b6 = ml>=c, b7 = tl>=c;
  int s = (b0+b1)+(b2+b3)+(b4+b5)+(b6+b7);
  int tr_ = (b0!=b7)+(b1!=b0)+(b2!=b1)+(b3!=b2)+(b4!=b3)+(b5!=b4)+(b6!=b5)+(b7!=b6);
  return (tr_<=2)? s : 9;
}

// ---------------- K1: per-image partial reductions + LBP code export ----
// Body identical to validated r8 k_reduce, plus: the two per-row codes each
// thread already computes are packed into a u16 and stored (coalesced) so
// k_main can skip gray staging + LBP entirely.
#define RSTRIDE 520
__global__ __launch_bounds__(256,4) void k_reduce(const float* __restrict__ frame,
     float4* __restrict__ part, unsigned short* __restrict__ codes16){
  const int blk = blockIdx.x;
  const int b = blk >> 6;
  const int s = blk & 63;
  const int r0 = s*8;
  const float4* F = (const float4*)(frame + (size_t)b*3*HWsz);
  __shared__ float sg[10*RSTRIDE];
  const int tid = threadIdx.x;
  float sy=0.f, su=0.f, sv=0.f;
  #pragma unroll
  for(int k=0;k<5;k++){
    int j = tid + 256*k;
    int row = j >> 7;
    int c4  = j & 127;
    int gy  = min(max(r0-1+row,0),HH-1);
    int fi  = gy*128 + c4;
    float4 r4 = F[fi];
    float4 g4 = F[65536  + fi];
    float4 b4 = F[131072 + fi];
    float4 gr;
    gr.x = grayf(r4.x,g4.x,b4.x);
    gr.y = grayf(r4.y,g4.y,b4.y);
    gr.z = grayf(r4.z,g4.z,b4.z);
    gr.w = grayf(r4.w,g4.w,b4.w);
    *(float4*)&sg[row*RSTRIDE + 4 + 4*c4] = gr;
    if(c4==0)   sg[row*RSTRIDE + 3]   = gr.x;
    if(c4==127) sg[row*RSTRIDE + 516] = gr.w;
    if(row>=1 && row<=8){
      sy += (gr.x+gr.y)+(gr.z+gr.w);
      float rs_=(r4.x+r4.y)+(r4.z+r4.w), gs_=(g4.x+g4.y)+(g4.z+g4.w), bs_=(b4.x+b4.y)+(b4.z+b4.w);
      su += -0.147f*rs_ - 0.289f*gs_ + 0.436f*bs_;
      sv +=  0.615f*rs_ - 0.515f*gs_ - 0.1f*bs_;
    }
  }
  __syncthreads();
  int cm = 0;
  {
    const float* base = sg + (2*tid + 3);
    float t0=base[0], t1=base[1], t2=base[2], t3=base[3];
    float m0=base[RSTRIDE], m1=base[RSTRIDE+1], m2=base[RSTRIDE+2], m3=base[RSTRIDE+3];
    #pragma unroll
    for(int R=1;R<=8;R++){
      const float* brow = base + (R+1)*RSTRIDE;
      float b0=brow[0], b1=brow[1], b2=brow[2], b3=brow[3];
      int c1 = lbp_code(t0,t1,t2, m0,m1,m2, b0,b1,b2);
      int c2 = lbp_code(t1,t2,t3, m1,m2,m3, b1,b2,b3);
      cm = max(cm, max(c1,c2));
      // byte (row*512 + 2tid) = code(col 2tid); byte+1 = code(col 2tid+1)
      codes16[(size_t)b*(HWsz/2) + (size_t)(r0+R-1)*(WW/2) + tid] =
          (unsigned short)(c1 | (c2<<8));
      t0=m0;t1=m1;t2=m2;t3=m3; m0=b0;m1=b1;m2=b2;m3=b3;
    }
  }
  #pragma unroll
  for(int off=32;off>=1;off>>=1){
    sy += __shfl_down(sy,off,64);
    su += __shfl_down(su,off,64);
    sv += __shfl_down(sv,off,64);
    cm = max(cm,__shfl_down(cm,off,64));
  }
  __shared__ float rs[3][4]; __shared__ int rm[4];
  int wave=tid>>6, lane=tid&63;
  if(lane==0){ rs[0][wave]=sy; rs[1][wave]=su; rs[2][wave]=sv; rm[wave]=cm; }
  __syncthreads();
  if(tid==0){
    part[blk] = make_float4((rs[0][0]+rs[0][1])+(rs[0][2]+rs[0][3]),
                            (rs[1][0]+rs[1][1])+(rs[1][2]+rs[1][3]),
                            (rs[2][0]+rs[2][1])+(rs[2][2]+rs[2][3]),
                            (float)max(max(rm[0],rm[1]),max(rm[2],rm[3])));
  }
}

// ---------------- K2: fused head + conv + mask + strength + watermark + RGB ----
// vs r8 (validated 152.3us): gray staging, sgt/sgb, scodetab, the LBP phase
// and its 2 barriers are DELETED. sA[3] is filled during staging from the
// precomputed codes (u32 = 4 packed u8) as code*inv_mx. inv_mx is computed
// by EVERY wave (own butterfly over the 64 partials' .w) so staging needs no
// barrier; wave0 additionally computes ssc. Conv / strength / final pass are
// byte-identical to r8 (measured-clean LDS shapes).
#define SAS 41
__global__ __launch_bounds__(256,6) void k_main(const float* __restrict__ frame,
    const int* __restrict__ wm, const float* __restrict__ sa_w, const float* __restrict__ sa_b,
    const float* __restrict__ ca_w1, const float* __restrict__ ca_w2,
    const float4* __restrict__ part, const unsigned char* __restrict__ codes8,
    float* __restrict__ out)
{
  const int b = blockIdx.z;
  const int tx0 = blockIdx.x*32, ty0 = blockIdx.y*32;
  const float* fr = frame + (size_t)b*3*HWsz;
  const float4* F4 = (const float4*)fr;

  __shared__ float sA[4][38][SAS];  // ch 0..2: zero-padded rgb; ch 3: lbp (code*inv_mx)
  __shared__ float ssc[4];          // 0..2 scale, 3 bias

  const int tid = threadIdx.x;

  // ---- head: every wave reduces max-code -> inv_mx; wave0 computes ssc ----
  float inv_mx;
  {
    float4 p4 = part[b*64 + (tid & 63)];
    float cmf = p4.w;
    #pragma unroll
    for(int off=1; off<64; off<<=1) cmf = fmaxf(cmf, __shfl_xor(cmf, off, 64));
    inv_mx = 1.0f / fmaxf(cmf, 1.0f);
    if(tid < 64){
      float sy=p4.x, su=p4.y, sv=p4.z;
      #pragma unroll
      for(int off=1; off<64; off<<=1){
        sy += __shfl_xor(sy, off, 64);
        su += __shfl_xor(su, off, 64);
        sv += __shfl_xor(sv, off, 64);
      }
      float p0 = sy * (1.0f/(float)HWsz);
      float p1 = su * (1.0f/(float)HWsz);
      float p2 = sv * (1.0f/(float)HWsz);
      float h0 = fmaxf(p0*ca_w1[0] + p1*ca_w1[1] + p2*ca_w1[2], 0.0f);
      float h1 = fmaxf(p0*ca_w1[3] + p1*ca_w1[4] + p2*ca_w1[5], 0.0f);
      float h2 = fmaxf(p0*ca_w1[6] + p1*ca_w1[7] + p2*ca_w1[8], 0.0f);
      if(tid < 3){
        float a = h0*ca_w2[tid*3+0] + h1*ca_w2[tid*3+1] + h2*ca_w2[tid*3+2];
        ssc[tid] = sigmoidf_(a);
      }
      if(tid == 3) ssc[3] = sa_b[0];
    }
  }

  // ---- staging: 38 rows (gy=ty0-3+lyA) x 10 quads; rgb + lbp channel ----
  for(int s = tid; s < 380; s += 256){
    int lyA = s / 10;           // 0..37 (sA row)
    int k   = s - lyA*10;       // 0..9
    int gy  = ty0 + lyA - 3;
    int ry  = min(max(gy,0),HH-1);
    int gx0 = tx0 + 4*k - 4;
    bool xin   = (gx0 >= 0) && (gx0 <= WW-4);
    bool rowin = (gy >= 0) && (gy < HH);
    float4 r4 = make_float4(0.f,0.f,0.f,0.f), g4 = r4, b4 = r4;
    unsigned int cw = 0u;
    if(xin){
      int fi = ry*(WW/4) + (gx0>>2);
      r4 = F4[fi]; g4 = F4[65536 + fi]; b4 = F4[131072 + fi];
      if(rowin)
        cw = *reinterpret_cast<const unsigned int*>(codes8 + (size_t)b*HWsz + (size_t)gy*WW + gx0);
    }
    float z = (rowin && xin) ? 1.0f : 0.0f;   // conv zero-pad
    int cb = 4*k;
    float* rp = &sA[0][lyA][cb];
    rp[0]          =r4.x*z; rp[1]          =r4.y*z; rp[2]          =r4.z*z; rp[3]          =r4.w*z;
    rp[38*SAS+0]   =g4.x*z; rp[38*SAS+1]   =g4.y*z; rp[38*SAS+2]   =g4.z*z; rp[38*SAS+3]   =g4.w*z;
    rp[2*38*SAS+0] =b4.x*z; rp[2*38*SAS+1] =b4.y*z; rp[2*38*SAS+2] =b4.z*z; rp[2*38*SAS+3] =b4.w*z;
    // lbp channel: code * inv_mx; cols 0 and 39 are never read by the conv,
    // zero them (matches r8 semantics). cw==0 already handles out-of-image.
    float l0 = (float)(cw      & 255u) * inv_mx;
    float l1 = (float)((cw>>8) & 255u) * inv_mx;
    float l2 = (float)((cw>>16)& 255u) * inv_mx;
    float l3 = (float)((cw>>24)& 255u) * inv_mx;
    float* lp = &sA[3][lyA][cb];
    lp[0] = (cb   >= 1 ) ? l0 : 0.0f;
    lp[1] = l1;
    lp[2] = l2;
    lp[3] = (cb+3 <= 38) ? l3 : 0.0f;
  }
  __syncthreads();

  // 7x7x4 conv; thread = (row ty, col-group t of 4 pixels). Scalar window loads.
  const int t  = tid & 7;
  const int ty = tid >> 3;
  float a0=ssc[3], a1=ssc[3], a2=ssc[3], a3=ssc[3];
  for(int ci=0;ci<4;ci++){
    #pragma unroll
    for(int ky=0;ky<7;ky++){
      const float* rowp = &sA[ci][ty+ky][4*t];
      float win[10];
      #pragma unroll
      for(int w=0;w<10;w++) win[w]=rowp[1+w];
      const float* wr = &sa_w[ci*49 + ky*7];
      #pragma unroll
      for(int kx=0;kx<7;kx++){
        float wt = wr[kx];
        a0 += win[kx+0]*wt;
        a1 += win[kx+1]*wt;
        a2 += win[kx+2]*wt;
        a3 += win[kx+3]*wt;
      }
    }
  }
  float m0=sigmoidf_(a0), m1=sigmoidf_(a1), m2=sigmoidf_(a2), m3=sigmoidf_(a3);
  {
    size_t midx = (size_t)(3*BB)*HWsz + (size_t)b*HWsz + (size_t)(ty0+ty)*WW + (size_t)(tx0+4*t);
    *reinterpret_cast<float4*>(out + midx) = make_float4(m0,m1,m2,m3);
  }

  // strength: mean of mask per 8x8 block via in-wave butterfly.
  float partl = (m0+m1)+(m2+m3);
  partl += __shfl_xor(partl, 1, 64);
  partl += __shfl_xor(partl, 8, 64);
  partl += __shfl_xor(partl, 16, 64);
  partl += __shfl_xor(partl, 32, 64);
  const float strength = partl * (1.0f/64.0f);

  // final: weighted yuv + rank-1 DCT delta -> rgb (scalar LDS reads)
  {
    const float sc0=ssc[0], sc1=ssc[1], sc2=ssc[2];
    const int bw = (tx0 + 4*t) >> 3;
    const float sgn = (float)(2*wm[bw]-1);
    const float d4 = (((ty+1)&2) ? -0.35355339059327373f : 0.35355339059327373f);
    const float delta = 0.05f * strength * sgn * d4;
    const float D3tab[8] = { 0.4157348061512726f,-0.0975451610080641f,-0.4903926402016152f,-0.2777851165098011f,
                             0.2777851165098011f, 0.4903926402016152f, 0.0975451610080641f,-0.4157348061512726f };
    float vr[4], vg[4], vb[4];
    #pragma unroll
    for(int j=0;j<4;j++){
      float r  = sA[0][ty+3][4*t+j+4];
      float g  = sA[1][ty+3][4*t+j+4];
      float bl = sA[2][ty+3][4*t+j+4];
      float yv = (0.299f*r + 0.587f*g + 0.114f*bl) * sc0;
      float uv = (-0.147f*r - 0.289f*g + 0.436f*bl) * sc1;
      float vv = ( 0.615f*r - 0.515f*g - 0.1f*bl) * sc2;
      float ym = yv + delta * D3tab[(t&1)*4 + j];
      vr[j] = ym + 1.14f*vv;
      vg[j] = ym - 0.395f*uv - 0.581f*vv;
      vb[j] = ym + 2.032f*uv;
    }
    size_t base = (size_t)(ty0+ty)*WW + (size_t)(tx0+4*t);
    *reinterpret_cast<float4*>(out + (size_t)(b*3+0)*HWsz + base) = make_float4(vr[0],vr[1],vr[2],vr[3]);
    *reinterpret_cast<float4*>(out + (size_t)(b*3+1)*HWsz + base) = make_float4(vg[0],vg[1],vg[2],vg[3]);
    *reinterpret_cast<float4*>(out + (size_t)(b*3+2)*HWsz + base) = make_float4(vb[0],vb[1],vb[2],vb[3]);
  }
}

extern "C" void kernel_launch(void* const* d_in, const int* in_sizes, int n_in,
                              void* d_out, int out_size, void* d_ws, size_t ws_size,
                              hipStream_t stream) {
  const float* frame = (const float*)d_in[0];
  const int*   wmark = (const int*)d_in[1];
  const float* sa_w  = (const float*)d_in[2];
  const float* sa_b  = (const float*)d_in[3];
  const float* ca_w1 = (const float*)d_in[4];
  const float* ca_w2 = (const float*)d_in[5];
  float* out = (float*)d_out;
  char* ws = (char*)d_ws;
  float4* part = (float4*)ws;                              // 1024 float4 = 16 KB
  unsigned short* codes16 = (unsigned short*)(ws + 16384); // 16*512*512 u8 = 4 MB
  const unsigned char* codes8 = (const unsigned char*)(ws + 16384);

  hipLaunchKernelGGL(k_reduce, dim3(1024),      dim3(256), 0, stream, frame, part, codes16);
  hipLaunchKernelGGL(k_main,   dim3(16,16,16),  dim3(256), 0, stream, frame, wmark, sa_w, sa_b, ca_w1, ca_w2, part, codes8, out);
}